// Round 5
// baseline (274.660 us; speedup 1.0000x reference)
//
#include <hip/hip_runtime.h>

// VectorQuantizer: fp32 buffers. in [32,64,64,64] NCHW, emb [512,64], out
// fp32. Must match numpy fp32 distance argmin bit-for-bit.
// Proven architecture (R5-R12, absmax 0.0): MFMA filter -> top-3 streaming
// select (index packed in low 9 mantissa bits, med3/max net) -> margin
// decision -> exact numpy fp32 replica for ambiguous rows (per-thread top-2
// re-rank; rare wave-cooperative full rescan).
// R14 post-mortem: LDS-staged codebook regressed (barriers re-coupled waves,
// occ 16.6%). Across R12/R13/R14 MFMA busy is constant ~10us, VALU ~30us,
// HBM ~7us, dur ~81-104us -> stall-dominated at 2-4 waves/SIMD.
// R15: SINGLE-PLANE fp16 filter. emb is tiny (|e|<=1/512), so stage the
// codebook as fp16(e * 2^14) (all normal-range, no denorm risk); x as plain
// fp16. Filter acc = 2^14*dot - 2^13*b2 via MFMA acc init. MFMA/iter 12->4,
// codebook 128KB->64KB (loads 4->2/iter), fragment build halves, VGPR down
// -> __launch_bounds__(256,7). Error bound (scaled domain, worst-case
// Sum|x| <= 150): eps <= 2^14*Sum|x e|*2^-10 + pack 0.125 + accum ~ 4.8;
// HMARGIN 10.0 >= 2*eps with ~2x headroom. Ambiguous rows (~10%) still
// resolved by the bit-exact replica paths => absmax 0.0 preserved.

#define NEMB 512
#define DIM 64
#define ROWS 64
#define HMARGIN 10.0f  // margin in scaled max-domain acc = 2^14*(dot - b2/2)

typedef unsigned int u32;
typedef unsigned short u16;
typedef __attribute__((ext_vector_type(8))) _Float16 f16x8;
typedef __attribute__((ext_vector_type(4))) float f32x4;

__device__ __forceinline__ u16 f2hbits(float f) {  // fp32 -> fp16 bits (RNE)
  union { _Float16 h; u16 u; } cv;
  cv.h = (_Float16)f;
  return cv.u;
}
__device__ __forceinline__ float fmed3(float a, float b, float c) {
  return __builtin_amdgcn_fmed3f(a, b, c);
}

// ---- prep: swizzled single-plane scaled-fp16 codebook + numpy-replica b2 --
// u16 layout: g*1024 + f*512 + r*32 + e ; g=row>>4, r=row&15, f=k>>5, e=k&31.
// A wave's 16-col fragment load at fixed f is 1KB contiguous (16B/lane).
// 128 blocks x 256 thr; b2 via shfl_xor tree == numpy pairwise-8 bit-exactly
// (proven R13/R14, absmax 0.0).
__global__ void vq_prep(const float* __restrict__ emb, u16* __restrict__ swz,
                        float* __restrict__ b2) {
#pragma clang fp contract(off)
  const int gtid = blockIdx.x * 256 + threadIdx.x;  // 0..32767
  {  // swz element task: e scaled by 2^14 (exact pow2), then RNE to fp16
    const int row = gtid >> 6, k = gtid & 63;
    const float ev = emb[gtid];
    swz[((row >> 4) << 10) + ((k >> 5) << 9) + ((row & 15) << 5) + (k & 31)] =
        f2hbits(ev * 16384.0f);
  }
  if (gtid < NEMB * 8) {  // b2 task: row = gtid>>3, j = gtid&7
    const int row = gtid >> 3, j = gtid & 7;
    const float* e = emb + (row << 6);
    float acc = e[j] * e[j];
#pragma unroll
    for (int i = 8; i < DIM; i += 8) acc = acc + e[i + j] * e[i + j];
    acc = acc + __shfl_xor(acc, 1);  // j=0: rr0+rr1
    acc = acc + __shfl_xor(acc, 2);  // j=0: (rr0+rr1)+(rr2+rr3)
    acc = acc + __shfl_xor(acc, 4);  // j=0: full pairwise-8 combine
    if (j == 0) b2[row] = acc;
  }
}

// ---- main kernel: 64 rows/block (R12-proven structure).
// wave wv: row-half rh=wv&1 (tiles 2rh,2rh+1), col-half ch=wv>>1 (256 cols).
__global__ __launch_bounds__(256, 7) void vq_mfma(
    const float* __restrict__ in, const float* __restrict__ emb,
    const u16* __restrict__ swz, const float* __restrict__ b2g,
    float* __restrict__ out) {
#pragma clang fp contract(off)
  __shared__ float xs[ROWS][DIM + 2];
  __shared__ float a2s[ROWS];
  __shared__ float b2s[NEMB];
  __shared__ float wsv1[ROWS][2], wsv2[ROWS][2], wsv3[ROWS][2];
  __shared__ int win[ROWS];
  __shared__ int queue[ROWS];
  __shared__ int qcnt;

  const int tid = threadIdx.x;
  const int blk = blockIdx.x;
  const int b = blk >> 6;
  const int hw0 = (blk & 63) << 6;
  const float* xbase = in + ((size_t)b << 18) + hw0;

  for (int i = tid; i < NEMB; i += 256) b2s[i] = b2g[i];
  if (tid == 0) qcnt = 0;

  {  // stage x tile (64 consecutive floats per wave = coalesced)
    const int h = tid & 63, cg = tid >> 6;
#pragma unroll
    for (int i = 0; i < 16; ++i) {
      const int c = cg + (i << 2);
      xs[h][c] = xbase[((size_t)c << 12) + h];
    }
  }
  __syncthreads();

  if (tid < ROWS) {  // a2 numpy pairwise-8 replica (re-rank input)
    const float* x = xs[tid];
    float rr[8];
#pragma unroll
    for (int j = 0; j < 8; ++j) {
      float acc = x[j] * x[j];
#pragma unroll
      for (int i = 8; i < DIM; i += 8) acc = acc + x[i + j] * x[i + j];
      rr[j] = acc;
    }
    a2s[tid] = ((rr[0] + rr[1]) + (rr[2] + rr[3])) + ((rr[4] + rr[5]) + (rr[6] + rr[7]));
  }

  const int lane = tid & 63;
  const int wv = tid >> 6;
  const int rh = wv & 1;   // row-half
  const int ch = wv >> 1;  // col-half
  const int rowl = lane & 15;
  const int quad = lane >> 4;

  // A fragments (plain fp16 of x) for this wave's 2 row-tiles:
  // A[m=lane&15][k=quad*8+j]
  f16x8 ah[2][2];
#pragma unroll
  for (int ta = 0; ta < 2; ++ta) {
    const int a = (rh << 1) + ta;
    const float* xr = xs[(a << 4) + rowl];
#pragma unroll
    for (int f = 0; f < 2; ++f) {
      const int k0 = (f << 5) + (quad << 3);
      f16x8 vh;
#pragma unroll
      for (int j = 0; j < 8; ++j) vh[j] = (_Float16)xr[k0 + j];
      ah[ta][f] = vh;
    }
  }

  // ---- single pass over 256 cols: streaming top-3 MAXIMA of
  // acc = 2^14*dot - 2^13*b2, index packed in low 9 mantissa bits ----
  float v1[8], v2[8], v3[8];
#pragma unroll
  for (int i = 0; i < 8; ++i) { v1[i] = -3.0e38f; v2[i] = -3.0e38f; v3[i] = -3.0e38f; }

  const u16* cbase = swz + ((ch << 4) << 10);
  const int off = (rowl << 5) + (quad << 3);

  // preload group 0; rolled loop (unroll 1) with 1-deep clamped prefetch
  f16x8 nh0 = *(const f16x8*)(cbase + off);
  f16x8 nh1 = *(const f16x8*)(cbase + 512 + off);

#pragma unroll 1
  for (int t = 0; t < 16; ++t) {
    const f16x8 bh0 = nh0, bh1 = nh1;
    {  // prefetch next group (clamped: last iter re-loads, harmless)
      const int tn = t < 15 ? t + 1 : 15;
      const u16* gb = cbase + (tn << 10);
      nh0 = *(const f16x8*)(gb + off);
      nh1 = *(const f16x8*)(gb + 512 + off);
    }
    const int n = (ch << 8) + (t << 4) + rowl;
    const float nb2 = b2s[n] * -8192.0f;  // -2^13*b2 (exact pow2 scale)
    const u32 nbits = (u32)n;
#pragma unroll
    for (int ta = 0; ta < 2; ++ta) {
      f32x4 acc = {nb2, nb2, nb2, nb2};
      acc = __builtin_amdgcn_mfma_f32_16x16x32_f16(ah[ta][0], bh0, acc, 0, 0, 0);
      acc = __builtin_amdgcn_mfma_f32_16x16x32_f16(ah[ta][1], bh1, acc, 0, 0, 0);
#pragma unroll
      for (int r = 0; r < 4; ++r) {
        const int i = (ta << 2) + r;
        const float cp =
            __uint_as_float((__float_as_uint(acc[r]) & 0xFFFFFE00u) | nbits);
        v3[i] = fmed3(v2[i], cp, v3[i]);
        v2[i] = fmed3(v1[i], cp, v2[i]);
        v1[i] = fmaxf(v1[i], cp);
      }
    }
  }

  // butterfly top-3 merge across the 16 column lanes (max domain); packed
  // values carry their indices, so the merge is pure med3/max
#pragma unroll
  for (int m = 1; m < 16; m <<= 1) {
#pragma unroll
    for (int i = 0; i < 8; ++i) {
      const float o1 = __shfl_xor(v1[i], m);
      const float o2 = __shfl_xor(v2[i], m);
      const float o3 = __shfl_xor(v3[i], m);
      v3[i] = fmed3(v2[i], o1, v3[i]);
      v2[i] = fmed3(v1[i], o1, v2[i]);
      v1[i] = fmaxf(v1[i], o1);
      v3[i] = fmed3(v2[i], o2, v3[i]);
      v2[i] = fmed3(v1[i], o2, v2[i]);
      v3[i] = fmaxf(v3[i], o3);
    }
  }
  if (rowl == 0) {  // publish per col-half slot
#pragma unroll
    for (int ta = 0; ta < 2; ++ta)
#pragma unroll
      for (int r = 0; r < 4; ++r) {
        const int row = (((rh << 1) + ta) << 4) + (quad << 2) + r;
        const int i = (ta << 2) + r;
        wsv1[row][ch] = v1[i]; wsv2[row][ch] = v2[i]; wsv3[row][ch] = v3[i];
      }
  }
  __syncthreads();

  // ---- cross-half merge + decision (scaled max domain) ----
  if (tid < ROWS) {
    float m1 = wsv1[tid][0], m2v = wsv2[tid][0], m3 = wsv3[tid][0];
    const float u1 = wsv1[tid][1], u2 = wsv2[tid][1], u3 = wsv3[tid][1];
    m3 = fmed3(m2v, u1, m3);
    m2v = fmed3(m1, u1, m2v);
    m1 = fmaxf(m1, u1);
    m3 = fmed3(m2v, u2, m3);
    m2v = fmed3(m1, u2, m2v);
    m3 = fmaxf(m3, u3);
    const int j1 = (int)(__float_as_uint(m1) & 0x1FFu);
    const int j2 = (int)(__float_as_uint(m2v) & 0x1FFu);

    if (m2v < m1 - HMARGIN) {
      win[tid] = j1;  // unambiguous
    } else if (m3 < m1 - HMARGIN) {
      // true argmin in {j1,j2}: exact numpy fp32 re-rank, first-min tie rule
      const float a2 = a2s[tid];
      const float* x = xs[tid];
      const float* e1p = emb + (j1 << 6);
      const float* e2p = emb + (j2 << 6);
      float acc1 = 0.f, acc2 = 0.f;
#pragma unroll
      for (int j = 0; j < DIM; ++j) {
        acc1 = fmaf(x[j], e1p[j], acc1);
        acc2 = fmaf(x[j], e2p[j], acc2);
      }
      const float t1 = a2 + b2s[j1];
      const float t2 = a2 + b2s[j2];
      const float d1 = t1 - 2.0f * acc1;
      const float d2 = t2 - 2.0f * acc2;
      win[tid] = (d2 < d1 || (d2 == d1 && j2 < j1)) ? j2 : j1;
    } else {  // >=3 within margin: full exact rescan (rare)
      const int p = atomicAdd(&qcnt, 1);
      queue[p] = tid;
    }
  }
  __syncthreads();

  // ---- rare fallback: wave-cooperative bit-exact numpy fp32 rescan ----
  const int nq = qcnt;
  for (int qi = wv; qi < nq; qi += 4) {
    const int row = queue[qi];
    const float a2 = a2s[row];
    const float* x = xs[row];  // broadcast LDS reads
    float bd = 3.0e38f;
    int bi = 1 << 30;
#pragma unroll 1
    for (int c = 0; c < 8; ++c) {
      const int k = (c << 6) + lane;
      const float* e = emb + (k << 6);
      float acc = 0.f;
#pragma unroll
      for (int j = 0; j < DIM; ++j) acc = fmaf(x[j], e[j], acc);
      const float tt = a2 + b2s[k];  // fl(a2+b2)
      const float u = 2.0f * acc;    // fl(2ab)
      const float d = tt - u;        // fl(t-u)
      if (d < bd || (d == bd && k < bi)) { bd = d; bi = k; }
    }
#pragma unroll
    for (int m = 1; m < 64; m <<= 1) {  // numpy first-min tie rule
      const float od = __shfl_xor(bd, m);
      const int oi = __shfl_xor(bi, m);
      if (od < bd || (od == bd && oi < bi)) { bd = od; bi = oi; }
    }
    if (lane == 0) win[row] = bi;
  }
  __syncthreads();

  {  // fold q into xs in place: batched 8+8 (concurrent emb-row loads,
     // bounded register pressure), fl(x + fl(q-x))
    const int r0 = wv << 4;
#pragma unroll
    for (int half = 0; half < 2; ++half) {
      const int rb = r0 + (half << 3);
      int wn[8];
#pragma unroll
      for (int r = 0; r < 8; ++r) wn[r] = win[rb + r];
      float qv[8];
#pragma unroll
      for (int r = 0; r < 8; ++r) qv[r] = emb[(wn[r] << 6) + lane];
#pragma unroll
      for (int r = 0; r < 8; ++r) {
        const float xv = xs[rb + r][lane];
        xs[rb + r][lane] = xv + (qv[r] - xv);
      }
    }
  }
  __syncthreads();

  {  // store: coalesced (lane = h)
    const int h = tid & 63, cg = tid >> 6;
    float* obase = out + ((size_t)b << 18) + hw0;
#pragma unroll
    for (int i = 0; i < 16; ++i) {
      const int c = cg + (i << 2);
      obase[((size_t)c << 12) + h] = xs[h][c];
    }
  }
}

// ---- fallback (R3, passed absmax 0.0): used only if ws too small ----
__global__ __launch_bounds__(256, 2) void vq_exact(
    const float* __restrict__ in, const float* __restrict__ emb,
    float* __restrict__ out, int nvec) {
#pragma clang fp contract(off)
  __shared__ float b2s[NEMB];
  for (int r = threadIdx.x; r < NEMB; r += 256) {
    const float* e = emb + r * DIM;
    float rr[8];
#pragma unroll
    for (int j = 0; j < 8; ++j) {
      float acc = e[j] * e[j];
#pragma unroll
      for (int i = 8; i < DIM; i += 8) acc = acc + e[i + j] * e[i + j];
      rr[j] = acc;
    }
    b2s[r] = ((rr[0] + rr[1]) + (rr[2] + rr[3])) + ((rr[4] + rr[5]) + (rr[6] + rr[7]));
  }
  __syncthreads();
  const int vec = blockIdx.x * 256 + threadIdx.x;
  if (vec >= nvec) return;
  const int b = vec >> 12, hw = vec & 4095;
  const float* xp = in + ((size_t)b << 18) + hw;
  float x[DIM];
#pragma unroll
  for (int j = 0; j < DIM; ++j) x[j] = xp[(size_t)j << 12];
  float a2;
  {
    float rr[8];
#pragma unroll
    for (int j = 0; j < 8; ++j) {
      float acc = x[j] * x[j];
#pragma unroll
      for (int i = 8; i < DIM; i += 8) acc = acc + x[i + j] * x[i + j];
      rr[j] = acc;
    }
    a2 = ((rr[0] + rr[1]) + (rr[2] + rr[3])) + ((rr[4] + rr[5]) + (rr[6] + rr[7]));
  }
  float best = 3.0e38f;
  int bi = 0;
  for (int k0 = 0; k0 < NEMB; k0 += 4) {
    const float *e0 = emb + ((k0 + 0) << 6), *e1 = emb + ((k0 + 1) << 6);
    const float *e2 = emb + ((k0 + 2) << 6), *e3 = emb + ((k0 + 3) << 6);
    float c0 = 0.f, c1 = 0.f, c2 = 0.f, c3 = 0.f;
#pragma unroll
    for (int j = 0; j < DIM; ++j) {
      const float xj = x[j];
      c0 = fmaf(xj, e0[j], c0); c1 = fmaf(xj, e1[j], c1);
      c2 = fmaf(xj, e2[j], c2); c3 = fmaf(xj, e3[j], c3);
    }
    float cc[4] = {c0, c1, c2, c3};
#pragma unroll
    for (int q = 0; q < 4; ++q) {
      const float t = a2 + b2s[k0 + q];
      const float u = 2.0f * cc[q];
      const float d = t - u;
      if (d < best) { best = d; bi = k0 + q; }
    }
  }
  const float* ew = emb + (bi << 6);
  float* op = out + ((size_t)b << 18) + hw;
#pragma unroll
  for (int c = 0; c < DIM; ++c) {
    const float xv = x[c];
    op[(size_t)c << 12] = xv + (ew[c] - xv);
  }
}

extern "C" void kernel_launch(void* const* d_in, const int* in_sizes, int n_in,
                              void* d_out, int out_size, void* d_ws, size_t ws_size,
                              hipStream_t stream) {
  const float* in;
  const float* emb;
  int in_elems;
  if (n_in >= 2 && in_sizes[0] == NEMB * DIM && in_sizes[1] != NEMB * DIM) {
    emb = (const float*)d_in[0]; in = (const float*)d_in[1]; in_elems = in_sizes[1];
  } else {
    in = (const float*)d_in[0]; emb = (const float*)d_in[1]; in_elems = in_sizes[0];
  }
  float* out = (float*)d_out;
  const int nvec = in_elems / DIM;
  const size_t swzB = (size_t)NEMB * DIM * sizeof(u16);  // single fp16 plane
  const size_t need = swzB + NEMB * sizeof(float);

  if (ws_size >= need && d_ws != nullptr && (nvec % ROWS) == 0 &&
      (in_elems % (DIM * 4096)) == 0) {
    u16* swz = (u16*)d_ws;
    float* b2 = (float*)((char*)d_ws + swzB);
    vq_prep<<<dim3(NEMB * DIM / 256), dim3(256), 0, stream>>>(emb, swz, b2);
    vq_mfma<<<dim3(nvec / ROWS), dim3(256), 0, stream>>>(in, emb, swz, b2, out);
  } else {
    vq_exact<<<dim3((nvec + 255) / 256), dim3(256), 0, stream>>>(in, emb, out, nvec);
  }
}

// Round 6
// 210.817 us; speedup vs baseline: 1.3028x; 1.3028x over previous
//
#include <hip/hip_runtime.h>

// VectorQuantizer: fp32 buffers. in [32,64,64,64] NCHW, emb [512,64], out
// fp32. Must match numpy fp32 distance argmin bit-for-bit.
// Proven architecture (R5-R12, absmax 0.0): MFMA filter -> top-3 streaming
// select (index packed in low 9 mantissa bits, med3/max net) -> margin
// decision -> exact numpy fp32 replica for ambiguous rows (per-thread top-2
// re-rank; rare wave-cooperative full rescan).
// R15 (passed, absmax 0.0): single-plane fp16 filter. emb tiny (|e|<=1/512)
// -> codebook staged as fp16(e*2^14) (normal range), x as plain fp16;
// acc = 2^14*dot - 2^13*b2 via MFMA acc init. MFMA/iter 12->4, codebook
// 128KB->64KB, fragment build halved. Error bound (scaled domain):
// eps <= ~4.8; HMARGIN 10.0 >= 2*eps. Ambiguous rows resolved by the
// bit-exact replica paths => absmax 0.0 (hardware-verified in R15).
// R15 post-mortem: __launch_bounds__(256,7) forced VGPR=36 -> full scratch
// spill (FETCH 17.5->69MB, WRITE 33->140MB, dur 219us). Guideline-6 bite.
// R16: identical numerics, __launch_bounds__(256,4) (VGPR cap 128, no
// spill, still 4+ blocks/CU; LDS 21.5KB permits 7).

#define NEMB 512
#define DIM 64
#define ROWS 64
#define HMARGIN 10.0f  // margin in scaled max-domain acc = 2^14*(dot - b2/2)

typedef unsigned int u32;
typedef unsigned short u16;
typedef __attribute__((ext_vector_type(8))) _Float16 f16x8;
typedef __attribute__((ext_vector_type(4))) float f32x4;

__device__ __forceinline__ u16 f2hbits(float f) {  // fp32 -> fp16 bits (RNE)
  union { _Float16 h; u16 u; } cv;
  cv.h = (_Float16)f;
  return cv.u;
}
__device__ __forceinline__ float fmed3(float a, float b, float c) {
  return __builtin_amdgcn_fmed3f(a, b, c);
}

// ---- prep: swizzled single-plane scaled-fp16 codebook + numpy-replica b2 --
// u16 layout: g*1024 + f*512 + r*32 + e ; g=row>>4, r=row&15, f=k>>5, e=k&31.
// A wave's 16-col fragment load at fixed f is 1KB contiguous (16B/lane).
// 128 blocks x 256 thr; b2 via shfl_xor tree == numpy pairwise-8 bit-exactly
// (proven R13/R14/R15, absmax 0.0).
__global__ void vq_prep(const float* __restrict__ emb, u16* __restrict__ swz,
                        float* __restrict__ b2) {
#pragma clang fp contract(off)
  const int gtid = blockIdx.x * 256 + threadIdx.x;  // 0..32767
  {  // swz element task: e scaled by 2^14 (exact pow2), then RNE to fp16
    const int row = gtid >> 6, k = gtid & 63;
    const float ev = emb[gtid];
    swz[((row >> 4) << 10) + ((k >> 5) << 9) + ((row & 15) << 5) + (k & 31)] =
        f2hbits(ev * 16384.0f);
  }
  if (gtid < NEMB * 8) {  // b2 task: row = gtid>>3, j = gtid&7
    const int row = gtid >> 3, j = gtid & 7;
    const float* e = emb + (row << 6);
    float acc = e[j] * e[j];
#pragma unroll
    for (int i = 8; i < DIM; i += 8) acc = acc + e[i + j] * e[i + j];
    acc = acc + __shfl_xor(acc, 1);  // j=0: rr0+rr1
    acc = acc + __shfl_xor(acc, 2);  // j=0: (rr0+rr1)+(rr2+rr3)
    acc = acc + __shfl_xor(acc, 4);  // j=0: full pairwise-8 combine
    if (j == 0) b2[row] = acc;
  }
}

// ---- main kernel: 64 rows/block (R12-proven structure).
// wave wv: row-half rh=wv&1 (tiles 2rh,2rh+1), col-half ch=wv>>1 (256 cols).
__global__ __launch_bounds__(256, 4) void vq_mfma(
    const float* __restrict__ in, const float* __restrict__ emb,
    const u16* __restrict__ swz, const float* __restrict__ b2g,
    float* __restrict__ out) {
#pragma clang fp contract(off)
  __shared__ float xs[ROWS][DIM + 2];
  __shared__ float a2s[ROWS];
  __shared__ float b2s[NEMB];
  __shared__ float wsv1[ROWS][2], wsv2[ROWS][2], wsv3[ROWS][2];
  __shared__ int win[ROWS];
  __shared__ int queue[ROWS];
  __shared__ int qcnt;

  const int tid = threadIdx.x;
  const int blk = blockIdx.x;
  const int b = blk >> 6;
  const int hw0 = (blk & 63) << 6;
  const float* xbase = in + ((size_t)b << 18) + hw0;

  for (int i = tid; i < NEMB; i += 256) b2s[i] = b2g[i];
  if (tid == 0) qcnt = 0;

  {  // stage x tile (64 consecutive floats per wave = coalesced)
    const int h = tid & 63, cg = tid >> 6;
#pragma unroll
    for (int i = 0; i < 16; ++i) {
      const int c = cg + (i << 2);
      xs[h][c] = xbase[((size_t)c << 12) + h];
    }
  }
  __syncthreads();

  if (tid < ROWS) {  // a2 numpy pairwise-8 replica (re-rank input)
    const float* x = xs[tid];
    float rr[8];
#pragma unroll
    for (int j = 0; j < 8; ++j) {
      float acc = x[j] * x[j];
#pragma unroll
      for (int i = 8; i < DIM; i += 8) acc = acc + x[i + j] * x[i + j];
      rr[j] = acc;
    }
    a2s[tid] = ((rr[0] + rr[1]) + (rr[2] + rr[3])) + ((rr[4] + rr[5]) + (rr[6] + rr[7]));
  }

  const int lane = tid & 63;
  const int wv = tid >> 6;
  const int rh = wv & 1;   // row-half
  const int ch = wv >> 1;  // col-half
  const int rowl = lane & 15;
  const int quad = lane >> 4;

  // A fragments (plain fp16 of x) for this wave's 2 row-tiles:
  // A[m=lane&15][k=quad*8+j]
  f16x8 ah[2][2];
#pragma unroll
  for (int ta = 0; ta < 2; ++ta) {
    const int a = (rh << 1) + ta;
    const float* xr = xs[(a << 4) + rowl];
#pragma unroll
    for (int f = 0; f < 2; ++f) {
      const int k0 = (f << 5) + (quad << 3);
      f16x8 vh;
#pragma unroll
      for (int j = 0; j < 8; ++j) vh[j] = (_Float16)xr[k0 + j];
      ah[ta][f] = vh;
    }
  }

  // ---- single pass over 256 cols: streaming top-3 MAXIMA of
  // acc = 2^14*dot - 2^13*b2, index packed in low 9 mantissa bits ----
  float v1[8], v2[8], v3[8];
#pragma unroll
  for (int i = 0; i < 8; ++i) { v1[i] = -3.0e38f; v2[i] = -3.0e38f; v3[i] = -3.0e38f; }

  const u16* cbase = swz + ((ch << 4) << 10);
  const int off = (rowl << 5) + (quad << 3);

  // preload group 0; rolled loop (unroll 1) with 1-deep clamped prefetch
  f16x8 nh0 = *(const f16x8*)(cbase + off);
  f16x8 nh1 = *(const f16x8*)(cbase + 512 + off);

#pragma unroll 1
  for (int t = 0; t < 16; ++t) {
    const f16x8 bh0 = nh0, bh1 = nh1;
    {  // prefetch next group (clamped: last iter re-loads, harmless)
      const int tn = t < 15 ? t + 1 : 15;
      const u16* gb = cbase + (tn << 10);
      nh0 = *(const f16x8*)(gb + off);
      nh1 = *(const f16x8*)(gb + 512 + off);
    }
    const int n = (ch << 8) + (t << 4) + rowl;
    const float nb2 = b2s[n] * -8192.0f;  // -2^13*b2 (exact pow2 scale)
    const u32 nbits = (u32)n;
#pragma unroll
    for (int ta = 0; ta < 2; ++ta) {
      f32x4 acc = {nb2, nb2, nb2, nb2};
      acc = __builtin_amdgcn_mfma_f32_16x16x32_f16(ah[ta][0], bh0, acc, 0, 0, 0);
      acc = __builtin_amdgcn_mfma_f32_16x16x32_f16(ah[ta][1], bh1, acc, 0, 0, 0);
#pragma unroll
      for (int r = 0; r < 4; ++r) {
        const int i = (ta << 2) + r;
        const float cp =
            __uint_as_float((__float_as_uint(acc[r]) & 0xFFFFFE00u) | nbits);
        v3[i] = fmed3(v2[i], cp, v3[i]);
        v2[i] = fmed3(v1[i], cp, v2[i]);
        v1[i] = fmaxf(v1[i], cp);
      }
    }
  }

  // butterfly top-3 merge across the 16 column lanes (max domain); packed
  // values carry their indices, so the merge is pure med3/max
#pragma unroll
  for (int m = 1; m < 16; m <<= 1) {
#pragma unroll
    for (int i = 0; i < 8; ++i) {
      const float o1 = __shfl_xor(v1[i], m);
      const float o2 = __shfl_xor(v2[i], m);
      const float o3 = __shfl_xor(v3[i], m);
      v3[i] = fmed3(v2[i], o1, v3[i]);
      v2[i] = fmed3(v1[i], o1, v2[i]);
      v1[i] = fmaxf(v1[i], o1);
      v3[i] = fmed3(v2[i], o2, v3[i]);
      v2[i] = fmed3(v1[i], o2, v2[i]);
      v3[i] = fmaxf(v3[i], o3);
    }
  }
  if (rowl == 0) {  // publish per col-half slot
#pragma unroll
    for (int ta = 0; ta < 2; ++ta)
#pragma unroll
      for (int r = 0; r < 4; ++r) {
        const int row = (((rh << 1) + ta) << 4) + (quad << 2) + r;
        const int i = (ta << 2) + r;
        wsv1[row][ch] = v1[i]; wsv2[row][ch] = v2[i]; wsv3[row][ch] = v3[i];
      }
  }
  __syncthreads();

  // ---- cross-half merge + decision (scaled max domain) ----
  if (tid < ROWS) {
    float m1 = wsv1[tid][0], m2v = wsv2[tid][0], m3 = wsv3[tid][0];
    const float u1 = wsv1[tid][1], u2 = wsv2[tid][1], u3 = wsv3[tid][1];
    m3 = fmed3(m2v, u1, m3);
    m2v = fmed3(m1, u1, m2v);
    m1 = fmaxf(m1, u1);
    m3 = fmed3(m2v, u2, m3);
    m2v = fmed3(m1, u2, m2v);
    m3 = fmaxf(m3, u3);
    const int j1 = (int)(__float_as_uint(m1) & 0x1FFu);
    const int j2 = (int)(__float_as_uint(m2v) & 0x1FFu);

    if (m2v < m1 - HMARGIN) {
      win[tid] = j1;  // unambiguous
    } else if (m3 < m1 - HMARGIN) {
      // true argmin in {j1,j2}: exact numpy fp32 re-rank, first-min tie rule
      const float a2 = a2s[tid];
      const float* x = xs[tid];
      const float* e1p = emb + (j1 << 6);
      const float* e2p = emb + (j2 << 6);
      float acc1 = 0.f, acc2 = 0.f;
#pragma unroll
      for (int j = 0; j < DIM; ++j) {
        acc1 = fmaf(x[j], e1p[j], acc1);
        acc2 = fmaf(x[j], e2p[j], acc2);
      }
      const float t1 = a2 + b2s[j1];
      const float t2 = a2 + b2s[j2];
      const float d1 = t1 - 2.0f * acc1;
      const float d2 = t2 - 2.0f * acc2;
      win[tid] = (d2 < d1 || (d2 == d1 && j2 < j1)) ? j2 : j1;
    } else {  // >=3 within margin: full exact rescan (rare)
      const int p = atomicAdd(&qcnt, 1);
      queue[p] = tid;
    }
  }
  __syncthreads();

  // ---- rare fallback: wave-cooperative bit-exact numpy fp32 rescan ----
  const int nq = qcnt;
  for (int qi = wv; qi < nq; qi += 4) {
    const int row = queue[qi];
    const float a2 = a2s[row];
    const float* x = xs[row];  // broadcast LDS reads
    float bd = 3.0e38f;
    int bi = 1 << 30;
#pragma unroll 1
    for (int c = 0; c < 8; ++c) {
      const int k = (c << 6) + lane;
      const float* e = emb + (k << 6);
      float acc = 0.f;
#pragma unroll
      for (int j = 0; j < DIM; ++j) acc = fmaf(x[j], e[j], acc);
      const float tt = a2 + b2s[k];  // fl(a2+b2)
      const float u = 2.0f * acc;    // fl(2ab)
      const float d = tt - u;        // fl(t-u)
      if (d < bd || (d == bd && k < bi)) { bd = d; bi = k; }
    }
#pragma unroll
    for (int m = 1; m < 64; m <<= 1) {  // numpy first-min tie rule
      const float od = __shfl_xor(bd, m);
      const int oi = __shfl_xor(bi, m);
      if (od < bd || (od == bd && oi < bi)) { bd = od; bi = oi; }
    }
    if (lane == 0) win[row] = bi;
  }
  __syncthreads();

  {  // fold q into xs in place: batched 8+8 (concurrent emb-row loads,
     // bounded register pressure), fl(x + fl(q-x))
    const int r0 = wv << 4;
#pragma unroll
    for (int half = 0; half < 2; ++half) {
      const int rb = r0 + (half << 3);
      int wn[8];
#pragma unroll
      for (int r = 0; r < 8; ++r) wn[r] = win[rb + r];
      float qv[8];
#pragma unroll
      for (int r = 0; r < 8; ++r) qv[r] = emb[(wn[r] << 6) + lane];
#pragma unroll
      for (int r = 0; r < 8; ++r) {
        const float xv = xs[rb + r][lane];
        xs[rb + r][lane] = xv + (qv[r] - xv);
      }
    }
  }
  __syncthreads();

  {  // store: coalesced (lane = h)
    const int h = tid & 63, cg = tid >> 6;
    float* obase = out + ((size_t)b << 18) + hw0;
#pragma unroll
    for (int i = 0; i < 16; ++i) {
      const int c = cg + (i << 2);
      obase[((size_t)c << 12) + h] = xs[h][c];
    }
  }
}

// ---- fallback (R3, passed absmax 0.0): used only if ws too small ----
__global__ __launch_bounds__(256, 2) void vq_exact(
    const float* __restrict__ in, const float* __restrict__ emb,
    float* __restrict__ out, int nvec) {
#pragma clang fp contract(off)
  __shared__ float b2s[NEMB];
  for (int r = threadIdx.x; r < NEMB; r += 256) {
    const float* e = emb + r * DIM;
    float rr[8];
#pragma unroll
    for (int j = 0; j < 8; ++j) {
      float acc = e[j] * e[j];
#pragma unroll
      for (int i = 8; i < DIM; i += 8) acc = acc + e[i + j] * e[i + j];
      rr[j] = acc;
    }
    b2s[r] = ((rr[0] + rr[1]) + (rr[2] + rr[3])) + ((rr[4] + rr[5]) + (rr[6] + rr[7]));
  }
  __syncthreads();
  const int vec = blockIdx.x * 256 + threadIdx.x;
  if (vec >= nvec) return;
  const int b = vec >> 12, hw = vec & 4095;
  const float* xp = in + ((size_t)b << 18) + hw;
  float x[DIM];
#pragma unroll
  for (int j = 0; j < DIM; ++j) x[j] = xp[(size_t)j << 12];
  float a2;
  {
    float rr[8];
#pragma unroll
    for (int j = 0; j < 8; ++j) {
      float acc = x[j] * x[j];
#pragma unroll
      for (int i = 8; i < DIM; i += 8) acc = acc + x[i + j] * x[i + j];
      rr[j] = acc;
    }
    a2 = ((rr[0] + rr[1]) + (rr[2] + rr[3])) + ((rr[4] + rr[5]) + (rr[6] + rr[7]));
  }
  float best = 3.0e38f;
  int bi = 0;
  for (int k0 = 0; k0 < NEMB; k0 += 4) {
    const float *e0 = emb + ((k0 + 0) << 6), *e1 = emb + ((k0 + 1) << 6);
    const float *e2 = emb + ((k0 + 2) << 6), *e3 = emb + ((k0 + 3) << 6);
    float c0 = 0.f, c1 = 0.f, c2 = 0.f, c3 = 0.f;
#pragma unroll
    for (int j = 0; j < DIM; ++j) {
      const float xj = x[j];
      c0 = fmaf(xj, e0[j], c0); c1 = fmaf(xj, e1[j], c1);
      c2 = fmaf(xj, e2[j], c2); c3 = fmaf(xj, e3[j], c3);
    }
    float cc[4] = {c0, c1, c2, c3};
#pragma unroll
    for (int q = 0; q < 4; ++q) {
      const float t = a2 + b2s[k0 + q];
      const float u = 2.0f * cc[q];
      const float d = t - u;
      if (d < best) { best = d; bi = k0 + q; }
    }
  }
  const float* ew = emb + (bi << 6);
  float* op = out + ((size_t)b << 18) + hw;
#pragma unroll
  for (int c = 0; c < DIM; ++c) {
    const float xv = x[c];
    op[(size_t)c << 12] = xv + (ew[c] - xv);
  }
}

extern "C" void kernel_launch(void* const* d_in, const int* in_sizes, int n_in,
                              void* d_out, int out_size, void* d_ws, size_t ws_size,
                              hipStream_t stream) {
  const float* in;
  const float* emb;
  int in_elems;
  if (n_in >= 2 && in_sizes[0] == NEMB * DIM && in_sizes[1] != NEMB * DIM) {
    emb = (const float*)d_in[0]; in = (const float*)d_in[1]; in_elems = in_sizes[1];
  } else {
    in = (const float*)d_in[0]; emb = (const float*)d_in[1]; in_elems = in_sizes[0];
  }
  float* out = (float*)d_out;
  const int nvec = in_elems / DIM;
  const size_t swzB = (size_t)NEMB * DIM * sizeof(u16);  // single fp16 plane
  const size_t need = swzB + NEMB * sizeof(float);

  if (ws_size >= need && d_ws != nullptr && (nvec % ROWS) == 0 &&
      (in_elems % (DIM * 4096)) == 0) {
    u16* swz = (u16*)d_ws;
    float* b2 = (float*)((char*)d_ws + swzB);
    vq_prep<<<dim3(NEMB * DIM / 256), dim3(256), 0, stream>>>(emb, swz, b2);
    vq_mfma<<<dim3(nvec / ROWS), dim3(256), 0, stream>>>(in, emb, swz, b2, out);
  } else {
    vq_exact<<<dim3((nvec + 255) / 256), dim3(256), 0, stream>>>(in, emb, out, nvec);
  }
}